// Round 1
// baseline (707.275 us; speedup 1.0000x reference)
//
#include <hip/hip_runtime.h>

typedef unsigned short u16;
typedef unsigned int   u32;
typedef __attribute__((ext_vector_type(8))) short          short8;
typedef __attribute__((ext_vector_type(4))) unsigned short u16x4;
typedef __attribute__((ext_vector_type(4))) float          f32x4;

__device__ __forceinline__ u16 f2bf(float f) {
  u32 u = __float_as_uint(f);
  return (u16)((u + 0x7FFFu + ((u >> 16) & 1u)) >> 16);
}
__device__ __forceinline__ float bf2f(u16 h) {
  return __uint_as_float(((u32)h) << 16);
}

// ---------------------------------------------------------------------------
// Generic fp32-input GEMM via bf16 MFMA.
//   EMU=1: 3-term bf16x2 emulation (fp32-class accuracy)   EMU=0: plain bf16
//   OUT_BF16=1: write bf16, else fp32
// C[m,n] = sum_k A[m,k] * B[k,n].  BM=BN=128, BK=32, 256 threads (4 waves 2x2).
// LDS layout: tiles stored [row][k] with pitch 40 shorts (80 B) -> b128 frag
// reads are k-contiguous and ~conflict-free.
// ---------------------------------------------------------------------------
template<int EMU, int OUT_BF16>
__global__ __launch_bounds__(256)
void gemm_f32(const float* __restrict__ Ag, const float* __restrict__ Bg,
              void* __restrict__ Cg, int K, int lda, int ldb, int ldc,
              int tiles_n, long long sA, long long sB, long long sC)
{
  constexpr int LDP = 40;
  constexpr int TSZ = 128 * LDP;
  __shared__ u16 sm[(EMU ? 4 : 2) * TSZ];
  u16* const sAh = sm;
  u16* const sBh = sm + TSZ;
  u16* const sAl = sm + (EMU ? 2 : 0) * TSZ;
  u16* const sBl = sm + (EMU ? 3 : 1) * TSZ;

  const int bz = blockIdx.y;
  const float* A = Ag + (size_t)bz * (size_t)sA;
  const float* B = Bg + (size_t)bz * (size_t)sB;

  const int tm = blockIdx.x / tiles_n;
  const int tn = blockIdx.x - tm * tiles_n;
  const int t = threadIdx.x;
  const int lane = t & 63;
  const int wid = t >> 6;
  const int wr = wid >> 1, wc = wid & 1;
  const int lr = lane & 15, lq = lane >> 4;

  const int am  = t >> 1;            // A stage: row (0..127)
  const int akh = (t & 1) << 4;      // A stage: k half (0/16)
  const int bn  = t & 127;           // B stage: col (0..127)
  const int bkh = (t >> 7) << 4;     // B stage: k half (0/16)

  f32x4 acc[4][4];
#pragma unroll
  for (int i = 0; i < 4; ++i)
#pragma unroll
    for (int k = 0; k < 4; ++k)
      acc[i][k] = (f32x4){0.f, 0.f, 0.f, 0.f};

  for (int k0 = 0; k0 < K; k0 += 32) {
    // ---- stage A: global rows are k-contiguous, float4 loads
    {
      const float* ap = A + (size_t)(tm * 128 + am) * (size_t)lda + (k0 + akh);
#pragma unroll
      for (int c4 = 0; c4 < 4; ++c4) {
        f32x4 v = *(const f32x4*)(ap + 4 * c4);
        u16x4 hi, lo;
#pragma unroll
        for (int jj = 0; jj < 4; ++jj) {
          float fv = v[jj];
          u16 hb = f2bf(fv);
          hi[jj] = hb;
          if (EMU) lo[jj] = f2bf(fv - bf2f(hb));
        }
        *(u16x4*)(sAh + am * LDP + akh + 4 * c4) = hi;
        if (EMU) *(u16x4*)(sAl + am * LDP + akh + 4 * c4) = lo;
      }
    }
    // ---- stage B: per-thread walks k (16 scalar loads, coalesced across
    //      lanes along n), writes k-contiguous bf16x4 -> register transpose
    {
      const float* bp = B + (size_t)(k0 + bkh) * (size_t)ldb + (tn * 128 + bn);
      float v[16];
#pragma unroll
      for (int i = 0; i < 16; ++i) v[i] = bp[(size_t)i * (size_t)ldb];
#pragma unroll
      for (int c4 = 0; c4 < 4; ++c4) {
        u16x4 hi, lo;
#pragma unroll
        for (int jj = 0; jj < 4; ++jj) {
          float fv = v[c4 * 4 + jj];
          u16 hb = f2bf(fv);
          hi[jj] = hb;
          if (EMU) lo[jj] = f2bf(fv - bf2f(hb));
        }
        *(u16x4*)(sBh + bn * LDP + bkh + 4 * c4) = hi;
        if (EMU) *(u16x4*)(sBl + bn * LDP + bkh + 4 * c4) = lo;
      }
    }
    __syncthreads();
    // ---- fragments + MFMA
    short8 ah[4], bh[4], al[4], bl[4];
#pragma unroll
    for (int mi = 0; mi < 4; ++mi) {
      ah[mi] = *(const short8*)(sAh + (wr * 64 + mi * 16 + lr) * LDP + lq * 8);
      if (EMU) al[mi] = *(const short8*)(sAl + (wr * 64 + mi * 16 + lr) * LDP + lq * 8);
    }
#pragma unroll
    for (int ni = 0; ni < 4; ++ni) {
      bh[ni] = *(const short8*)(sBh + (wc * 64 + ni * 16 + lr) * LDP + lq * 8);
      if (EMU) bl[ni] = *(const short8*)(sBl + (wc * 64 + ni * 16 + lr) * LDP + lq * 8);
    }
#pragma unroll
    for (int mi = 0; mi < 4; ++mi)
#pragma unroll
      for (int ni = 0; ni < 4; ++ni) {
        acc[mi][ni] = __builtin_amdgcn_mfma_f32_16x16x32_bf16(ah[mi], bh[ni], acc[mi][ni], 0, 0, 0);
        if (EMU) {
          acc[mi][ni] = __builtin_amdgcn_mfma_f32_16x16x32_bf16(ah[mi], bl[ni], acc[mi][ni], 0, 0, 0);
          acc[mi][ni] = __builtin_amdgcn_mfma_f32_16x16x32_bf16(al[mi], bh[ni], acc[mi][ni], 0, 0, 0);
        }
      }
    __syncthreads();
  }
  // ---- epilogue: C/D layout col = lane&15, row = (lane>>4)*4 + reg
  const int rbase = tm * 128 + wr * 64;
  const int cbase = tn * 128 + wc * 64;
  if (OUT_BF16) {
    u16* C = (u16*)Cg + (size_t)bz * (size_t)sC;
#pragma unroll
    for (int mi = 0; mi < 4; ++mi)
#pragma unroll
      for (int ni = 0; ni < 4; ++ni) {
        const int r0 = rbase + mi * 16 + lq * 4;
        const int cc = cbase + ni * 16 + lr;
#pragma unroll
        for (int r = 0; r < 4; ++r)
          C[(size_t)(r0 + r) * (size_t)ldc + cc] = f2bf(acc[mi][ni][r]);
      }
  } else {
    float* C = (float*)Cg + (size_t)bz * (size_t)sC;
#pragma unroll
    for (int mi = 0; mi < 4; ++mi)
#pragma unroll
      for (int ni = 0; ni < 4; ++ni) {
        const int r0 = rbase + mi * 16 + lq * 4;
        const int cc = cbase + ni * 16 + lr;
#pragma unroll
        for (int r = 0; r < 4; ++r)
          C[(size_t)(r0 + r) * (size_t)ldc + cc] = acc[mi][ni][r];
      }
  }
}

// ---------------------------------------------------------------------------
// Fused column-softmax (over axis=1, i.e. over row index per (c,j) column) +
// transpose: PT[c][j][i] = bf16( exp(S[c,i,j]-m_cj) / sum_cj ).
// One block per (channel, 64-column tile); 256 threads.
// ---------------------------------------------------------------------------
__global__ __launch_bounds__(256)
void softmax_pt(const float* __restrict__ S, u16* __restrict__ PT)
{
  __shared__ float rm[4][64];
  __shared__ float rs[4][64];
  __shared__ u16 tile[64 * 66];   // pitch 66 -> conflict-free transposed writes
  const int c  = blockIdx.x >> 2;
  const int jt = blockIdx.x & 3;
  const int t  = threadIdx.x;
  const int jl = t & 63;
  const int qi = t >> 6;
  const int j  = jt * 64 + jl;
  const float* colp = S + (size_t)c * 65536 + j;

  // online max/sum over this thread's 64 rows of column j
  float m = -3.4e38f, s = 0.f;
  for (int i = qi * 64; i < qi * 64 + 64; ++i) {
    float v = colp[(size_t)i * 256];
    float nm = fmaxf(m, v);
    s = s * __expf(m - nm) + __expf(v - nm);
    m = nm;
  }
  rm[qi][jl] = m; rs[qi][jl] = s;
  __syncthreads();
  const float M = fmaxf(fmaxf(rm[0][jl], rm[1][jl]), fmaxf(rm[2][jl], rm[3][jl]));
  const float Ssum = rs[0][jl] * __expf(rm[0][jl] - M) + rs[1][jl] * __expf(rm[1][jl] - M)
                   + rs[2][jl] * __expf(rm[2][jl] - M) + rs[3][jl] * __expf(rm[3][jl] - M);
  const float rsum = 1.f / Ssum;

  u16* Pc = PT + (size_t)c * 65536;
  for (int it = 0; it < 4; ++it) {
    __syncthreads();   // previous iteration's tile reads done
#pragma unroll
    for (int r = 0; r < 16; ++r) {
      const int il = r * 4 + qi;
      float v = colp[(size_t)(it * 64 + il) * 256];
      float p = __expf(v - M) * rsum;
      tile[jl * 66 + il] = f2bf(p);
    }
    __syncthreads();
#pragma unroll
    for (int r = 0; r < 16; ++r) {
      const int jw = r * 4 + qi;
      Pc[(size_t)(jt * 64 + jw) * 256 + it * 64 + jl] = tile[jw * 66 + jl];
    }
  }
}

// ---------------------------------------------------------------------------
// Final bmm: out[c,i,j] = x[c,i,j] + sum_k h[c,i,k] * PT[c,j,k]   (plain bf16)
// Both operands are pre-laid-out k-contiguous -> trivial staging.
// ---------------------------------------------------------------------------
__global__ __launch_bounds__(256)
void attn_gemm(const u16* __restrict__ Hg, const u16* __restrict__ Pg,
               const float* __restrict__ Xg, float* __restrict__ Og)
{
  constexpr int LDP = 40;
  constexpr int TSZ = 128 * LDP;
  __shared__ u16 sm[2 * TSZ];
  u16* const sA = sm;
  u16* const sB = sm + TSZ;
  const int c = blockIdx.y;
  const u16* H = Hg + (size_t)c * 65536;
  const u16* P = Pg + (size_t)c * 65536;
  const int tm = blockIdx.x >> 1, tn = blockIdx.x & 1;
  const int t = threadIdx.x;
  const int lane = t & 63, wid = t >> 6;
  const int wr = wid >> 1, wc = wid & 1;
  const int lr = lane & 15, lq = lane >> 4;
  const int am = t >> 1, akh = (t & 1) << 4;

  f32x4 acc[4][4];
#pragma unroll
  for (int i = 0; i < 4; ++i)
#pragma unroll
    for (int k = 0; k < 4; ++k)
      acc[i][k] = (f32x4){0.f, 0.f, 0.f, 0.f};

  for (int k0 = 0; k0 < 256; k0 += 32) {
    {
      const u16* hp = H + (size_t)(tm * 128 + am) * 256 + k0 + akh;
      short8 v0 = *(const short8*)hp;
      short8 v1 = *(const short8*)(hp + 8);
      *(short8*)(sA + am * LDP + akh)     = v0;
      *(short8*)(sA + am * LDP + akh + 8) = v1;
      const u16* pp = P + (size_t)(tn * 128 + am) * 256 + k0 + akh;
      short8 w0 = *(const short8*)pp;
      short8 w1 = *(const short8*)(pp + 8);
      *(short8*)(sB + am * LDP + akh)     = w0;
      *(short8*)(sB + am * LDP + akh + 8) = w1;
    }
    __syncthreads();
    short8 af[4], bfr[4];
#pragma unroll
    for (int mi = 0; mi < 4; ++mi)
      af[mi] = *(const short8*)(sA + (wr * 64 + mi * 16 + lr) * LDP + lq * 8);
#pragma unroll
    for (int ni = 0; ni < 4; ++ni)
      bfr[ni] = *(const short8*)(sB + (wc * 64 + ni * 16 + lr) * LDP + lq * 8);
#pragma unroll
    for (int mi = 0; mi < 4; ++mi)
#pragma unroll
      for (int ni = 0; ni < 4; ++ni)
        acc[mi][ni] = __builtin_amdgcn_mfma_f32_16x16x32_bf16(af[mi], bfr[ni], acc[mi][ni], 0, 0, 0);
    __syncthreads();
  }

  const float* Xc = Xg + (size_t)c * 65536;
  float* Oc = Og + (size_t)c * 65536;
  const int rbase = tm * 128 + wr * 64;
  const int cbase = tn * 128 + wc * 64;
#pragma unroll
  for (int mi = 0; mi < 4; ++mi)
#pragma unroll
    for (int ni = 0; ni < 4; ++ni) {
      const int r0 = rbase + mi * 16 + lq * 4;
      const int cc = cbase + ni * 16 + lr;
#pragma unroll
      for (int r = 0; r < 4; ++r) {
        const size_t idx = (size_t)(r0 + r) * 256 + cc;
        Oc[idx] = Xc[idx] + acc[mi][ni][r];
      }
    }
}

// ---------------------------------------------------------------------------
extern "C" void kernel_launch(void* const* d_in, const int* in_sizes, int n_in,
                              void* d_out, int out_size, void* d_ws, size_t ws_size,
                              hipStream_t stream)
{
  (void)in_sizes; (void)n_in; (void)out_size; (void)ws_size;
  const float* x  = (const float*)d_in[0];
  const float* Wf = (const float*)d_in[1];
  const float* Wg = (const float*)d_in[2];
  const float* Wh = (const float*)d_in[3];
  float* S = (float*)d_out;                      // scores live in d_out
  char*  ws = (char*)d_ws;
  float* fb  = (float*)(ws);                     // f  : 134 MB @ 0
  float* gb  = (float*)(ws + 134217728);         // g  : 134 MB @ 128 MiB
  u16*   PTb = (u16*)(ws);                       // P^T: reuses f's slot
  u16*   hb  = (u16*)(ws + 134217728);           // h  : reuses g's slot

  dim3 blk(256, 1, 1);
  // f = Wf @ x, g = Wg @ x  (emulated fp32 accuracy)
  gemm_f32<1, 0><<<dim3(2048, 1, 1), blk, 0, stream>>>(Wf, x, fb, 512, 512, 65536, 65536, 512, 0, 0, 0);
  gemm_f32<1, 0><<<dim3(2048, 1, 1), blk, 0, stream>>>(Wg, x, gb, 512, 512, 65536, 65536, 512, 0, 0, 0);
  // S[c] = f[c] @ g[c]  (batched, emulated)
  gemm_f32<1, 0><<<dim3(4, 512, 1), blk, 0, stream>>>(fb, gb, S, 256, 256, 256, 256, 2, 65536, 65536, 65536);
  // P^T = softmax over rows, transposed, bf16  (overwrites f)
  softmax_pt<<<dim3(2048, 1, 1), blk, 0, stream>>>(S, PTb);
  // h = Wh @ x  (plain bf16, overwrites g)
  gemm_f32<0, 1><<<dim3(2048, 1, 1), blk, 0, stream>>>(Wh, x, hb, 512, 512, 65536, 65536, 512, 0, 0, 0);
  // out = x + h @ P  (plain bf16, overwrites S in d_out)
  attn_gemm<<<dim3(4, 512, 1), blk, 0, stream>>>(hb, PTb, x, S);
}

// Round 2
// 655.270 us; speedup vs baseline: 1.0794x; 1.0794x over previous
//
#include <hip/hip_runtime.h>

typedef unsigned short u16;
typedef unsigned int   u32;
typedef __attribute__((ext_vector_type(8))) short short8;
typedef __attribute__((ext_vector_type(4))) float f32x4;

__device__ __forceinline__ u16 f2bf(float f) {           // round-to-nearest-even
  u32 u = __float_as_uint(f);
  return (u16)((u + 0x7FFFu + ((u >> 16) & 1u)) >> 16);
}

// split 16 fp32 (k-consecutive) into trunc-hi u16 pairs + rne-lo u16 pairs
__device__ __forceinline__ void split16(const float* v, u32* hi, u32* lo) {
#pragma unroll
  for (int q = 0; q < 8; ++q) {
    float a = v[2*q], b = v[2*q+1];
    u32 ua = __float_as_uint(a), ub = __float_as_uint(b);
    hi[q] = __builtin_amdgcn_perm(ub, ua, 0x07060302u);   // {trunc(a), trunc(b)}
    float la = a - __uint_as_float(ua & 0xFFFF0000u);
    float lb = b - __uint_as_float(ub & 0xFFFF0000u);
    u32 d;
    asm("v_cvt_pk_bf16_f32 %0, %1, %2" : "=v"(d) : "v"(la), "v"(lb));
    lo[q] = d;
  }
}
__device__ __forceinline__ void cvt16(const float* v, u32* hi) {   // rne pairs
#pragma unroll
  for (int q = 0; q < 8; ++q) {
    u32 d;
    asm("v_cvt_pk_bf16_f32 %0, %1, %2" : "=v"(d) : "v"(v[2*q]), "v"(v[2*q+1]));
    hi[q] = d;
  }
}

constexpr int LDP = 40;          // LDS pitch in u16 (80 B = 16B-aligned rows)

// ---------------------------------------------------------------------------
// conv_fg: [f;g] = [Wf;Wg] @ x   (EMU bf16-pair, fp32-class accuracy)
// M=1024, K=512, N=65536. f rows (<512) -> fhi/flo bf16 split; g rows -> fp32.
// ---------------------------------------------------------------------------
__global__ __launch_bounds__(256)
void conv_fg(const float* __restrict__ Wf, const float* __restrict__ Wg,
             const float* __restrict__ x, u16* __restrict__ fhi,
             u16* __restrict__ flo, float* __restrict__ gout)
{
  __shared__ u16 sAh[128*LDP], sAl[128*LDP], sBh[128*LDP], sBl[128*LDP];
  const int bid = blockIdx.x;
  const int wg  = (bid & 7) * 512 + (bid >> 3);          // XCD swizzle (4096%8==0)
  const int tm = wg / 512, tn = wg % 512;
  const int t = threadIdx.x, lane = t & 63, wid = t >> 6;
  const int wr = wid >> 1, wc = wid & 1, lr = lane & 15, lq = lane >> 4;
  const int am = t >> 1, akh = (t & 1) << 4;
  const int bn = t & 127, bkh = (t >> 7) << 4;

  const bool fmode = (tm < 4);
  const float* Asrc = fmode ? (Wf + (size_t)(tm*128)*512) : (Wg + (size_t)(tm-4)*128*512);

  f32x4 acc[4][4];
#pragma unroll
  for (int i = 0; i < 4; ++i)
#pragma unroll
    for (int k = 0; k < 4; ++k) acc[i][k] = (f32x4){0,0,0,0};

  for (int k0 = 0; k0 < 512; k0 += 32) {
    { // A stage
      const float* ap = Asrc + (size_t)am*512 + k0 + akh;
      float v[16];
#pragma unroll
      for (int c4 = 0; c4 < 4; ++c4) { f32x4 w = *(const f32x4*)(ap + 4*c4);
        v[4*c4]=w[0]; v[4*c4+1]=w[1]; v[4*c4+2]=w[2]; v[4*c4+3]=w[3]; }
      u32 hi[8], lo[8]; split16(v, hi, lo);
      u32* dh = (u32*)(sAh + am*LDP + akh); u32* dl = (u32*)(sAl + am*LDP + akh);
#pragma unroll
      for (int q = 0; q < 8; ++q) { dh[q] = hi[q]; dl[q] = lo[q]; }
    }
    { // B stage (x rows strided)
      const float* bp = x + (size_t)(k0 + bkh)*65536 + (tn*128 + bn);
      float v[16];
#pragma unroll
      for (int i = 0; i < 16; ++i) v[i] = bp[(size_t)i*65536];
      u32 hi[8], lo[8]; split16(v, hi, lo);
      u32* dh = (u32*)(sBh + bn*LDP + bkh); u32* dl = (u32*)(sBl + bn*LDP + bkh);
#pragma unroll
      for (int q = 0; q < 8; ++q) { dh[q] = hi[q]; dl[q] = lo[q]; }
    }
    __syncthreads();
    short8 ah[4], al[4], bh[4], bl[4];
#pragma unroll
    for (int mi = 0; mi < 4; ++mi) {
      ah[mi] = *(const short8*)(sAh + (wr*64 + mi*16 + lr)*LDP + lq*8);
      al[mi] = *(const short8*)(sAl + (wr*64 + mi*16 + lr)*LDP + lq*8);
    }
#pragma unroll
    for (int ni = 0; ni < 4; ++ni) {
      bh[ni] = *(const short8*)(sBh + (wc*64 + ni*16 + lr)*LDP + lq*8);
      bl[ni] = *(const short8*)(sBl + (wc*64 + ni*16 + lr)*LDP + lq*8);
    }
#pragma unroll
    for (int mi = 0; mi < 4; ++mi)
#pragma unroll
      for (int ni = 0; ni < 4; ++ni) {
        acc[mi][ni] = __builtin_amdgcn_mfma_f32_16x16x32_bf16(ah[mi], bh[ni], acc[mi][ni], 0,0,0);
        acc[mi][ni] = __builtin_amdgcn_mfma_f32_16x16x32_bf16(ah[mi], bl[ni], acc[mi][ni], 0,0,0);
        acc[mi][ni] = __builtin_amdgcn_mfma_f32_16x16x32_bf16(al[mi], bh[ni], acc[mi][ni], 0,0,0);
      }
    __syncthreads();
  }

  const int rbase = tm*128 + wr*64, cbase = tn*128 + wc*64;
#pragma unroll
  for (int mi = 0; mi < 4; ++mi)
#pragma unroll
    for (int ni = 0; ni < 4; ++ni) {
      const int r0 = rbase + mi*16 + lq*4, cc = cbase + ni*16 + lr;
#pragma unroll
      for (int r = 0; r < 4; ++r) {
        float val = acc[mi][ni][r];
        if (fmode) {
          const size_t idx = (size_t)(r0 + r)*65536 + cc;
          u32 u = __float_as_uint(val);
          fhi[idx] = (u16)(u >> 16);
          flo[idx] = f2bf(val - __uint_as_float(u & 0xFFFF0000u));
        } else {
          gout[(size_t)(r0 + r - 512)*65536 + cc] = val;
        }
      }
    }
}

// ---------------------------------------------------------------------------
// scores: per (c, row-half tm): S = f[c] @ g[c] (EMU), then column-partial
// softmax stats + P = exp(S - m_blk) bf16 written IN PLACE over fhi rows tm.
// stats (m,s) per (c,tm,j) written into flo's own rows (race-safe).
// 512 threads (8 waves 2x4), block tile 128x256, K=256.
// ---------------------------------------------------------------------------
__global__ __launch_bounds__(512)
void scores_kernel(u16* fhi, const u16* __restrict__ flo_ro, const float* __restrict__ g,
                   char* statsb)
{
  __shared__ u16 sAh[128*LDP], sAl[128*LDP], sBh[256*LDP], sBl[256*LDP];
  __shared__ float colmax[2][256], colsum[2][256];
  const int c = blockIdx.x >> 1, tm = blockIdx.x & 1;
  const int t = threadIdx.x, lane = t & 63, wid = t >> 6;
  const int wr = wid >> 2, wc = wid & 3, lr = lane & 15, lq = lane >> 4;
  const int arow = t >> 2, akq = (t & 3) * 8;            // A stage mapping
  const int bj = t & 255, bkh = (t >> 8) << 4;           // B stage mapping

  const size_t cb = (size_t)c * 65536;
  f32x4 acc[4][4];
#pragma unroll
  for (int i = 0; i < 4; ++i)
#pragma unroll
    for (int k = 0; k < 4; ++k) acc[i][k] = (f32x4){0,0,0,0};

  for (int k0 = 0; k0 < 256; k0 += 32) {
    { // A: copy f hi/lo
      const size_t src = cb + (size_t)(tm*128 + arow)*256 + k0 + akq;
      *(short8*)(sAh + arow*LDP + akq) = *(const short8*)(fhi + src);
      *(short8*)(sAl + arow*LDP + akq) = *(const short8*)(flo_ro + src);
    }
    { // B: g fp32 strided -> trunc/rne split
      const float* bp = g + cb + (size_t)(k0 + bkh)*256 + bj;
      float v[16];
#pragma unroll
      for (int i = 0; i < 16; ++i) v[i] = bp[(size_t)i*256];
      u32 hi[8], lo[8]; split16(v, hi, lo);
      u32* dh = (u32*)(sBh + bj*LDP + bkh); u32* dl = (u32*)(sBl + bj*LDP + bkh);
#pragma unroll
      for (int q = 0; q < 8; ++q) { dh[q] = hi[q]; dl[q] = lo[q]; }
    }
    __syncthreads();
    short8 ah[4], al[4], bh[4], bl[4];
#pragma unroll
    for (int mi = 0; mi < 4; ++mi) {
      ah[mi] = *(const short8*)(sAh + (wr*64 + mi*16 + lr)*LDP + lq*8);
      al[mi] = *(const short8*)(sAl + (wr*64 + mi*16 + lr)*LDP + lq*8);
    }
#pragma unroll
    for (int ni = 0; ni < 4; ++ni) {
      bh[ni] = *(const short8*)(sBh + (wc*64 + ni*16 + lr)*LDP + lq*8);
      bl[ni] = *(const short8*)(sBl + (wc*64 + ni*16 + lr)*LDP + lq*8);
    }
#pragma unroll
    for (int mi = 0; mi < 4; ++mi)
#pragma unroll
      for (int ni = 0; ni < 4; ++ni) {
        acc[mi][ni] = __builtin_amdgcn_mfma_f32_16x16x32_bf16(ah[mi], bh[ni], acc[mi][ni], 0,0,0);
        acc[mi][ni] = __builtin_amdgcn_mfma_f32_16x16x32_bf16(ah[mi], bl[ni], acc[mi][ni], 0,0,0);
        acc[mi][ni] = __builtin_amdgcn_mfma_f32_16x16x32_bf16(al[mi], bh[ni], acc[mi][ni], 0,0,0);
      }
    __syncthreads();
  }

  // ---- epilogue: column max (block-level), expsum, P write, stats write
#pragma unroll
  for (int ni = 0; ni < 4; ++ni) {
    const int cc = wc*64 + ni*16 + lr;
    float m = -3.4e38f;
#pragma unroll
    for (int mi = 0; mi < 4; ++mi)
#pragma unroll
      for (int r = 0; r < 4; ++r) m = fmaxf(m, acc[mi][ni][r]);
    m = fmaxf(m, __shfl_xor(m, 16));
    m = fmaxf(m, __shfl_xor(m, 32));
    colmax[wr][cc] = m;
  }
  __syncthreads();
  float Mv[4];
#pragma unroll
  for (int ni = 0; ni < 4; ++ni) {
    const int cc = wc*64 + ni*16 + lr;
    Mv[ni] = fmaxf(colmax[0][cc], colmax[1][cc]);
    float s = 0.f;
#pragma unroll
    for (int mi = 0; mi < 4; ++mi)
#pragma unroll
      for (int r = 0; r < 4; ++r) s += __expf(acc[mi][ni][r] - Mv[ni]);
    s += __shfl_xor(s, 16);
    s += __shfl_xor(s, 32);
    colsum[wr][cc] = s;
  }
  __syncthreads();
  if (t < 256) {
    const int j = t;
    float Mj = fmaxf(colmax[0][j], colmax[1][j]);
    float Sj = colsum[0][j] + colsum[1][j];
    *(float2*)(statsb + (size_t)c*131072 + (size_t)tm*65536 + (size_t)j*8) =
        make_float2(Mj, Sj);
  }
  // P = exp(acc - M_blk) bf16, in place over fhi (this block's own rows)
#pragma unroll
  for (int mi = 0; mi < 4; ++mi)
#pragma unroll
    for (int ni = 0; ni < 4; ++ni) {
      const int cc = wc*64 + ni*16 + lr;
      const int ri = wr*64 + mi*16 + lq*4;
#pragma unroll
      for (int r = 0; r < 4; ++r) {
        float p = __expf(acc[mi][ni][r] - Mv[ni]);
        fhi[cb + (size_t)(tm*128 + ri + r)*256 + cc] = f2bf(p);
      }
    }
}

// ---------------------------------------------------------------------------
// conv_h: h = Wh @ x, plain bf16 (rne), output bf16.
// ---------------------------------------------------------------------------
__global__ __launch_bounds__(256)
void conv_h(const float* __restrict__ Wh, const float* __restrict__ x,
            u16* __restrict__ hout)
{
  __shared__ u16 sA[128*LDP], sB[128*LDP];
  const int bid = blockIdx.x;
  const int wg  = (bid & 7) * 256 + (bid >> 3);          // 2048%8==0
  const int tm = wg / 512, tn = wg % 512;
  const int t = threadIdx.x, lane = t & 63, wid = t >> 6;
  const int wr = wid >> 1, wc = wid & 1, lr = lane & 15, lq = lane >> 4;
  const int am = t >> 1, akh = (t & 1) << 4;
  const int bn = t & 127, bkh = (t >> 7) << 4;

  f32x4 acc[4][4];
#pragma unroll
  for (int i = 0; i < 4; ++i)
#pragma unroll
    for (int k = 0; k < 4; ++k) acc[i][k] = (f32x4){0,0,0,0};

  for (int k0 = 0; k0 < 512; k0 += 32) {
    {
      const float* ap = Wh + (size_t)(tm*128 + am)*512 + k0 + akh;
      float v[16];
#pragma unroll
      for (int c4 = 0; c4 < 4; ++c4) { f32x4 w = *(const f32x4*)(ap + 4*c4);
        v[4*c4]=w[0]; v[4*c4+1]=w[1]; v[4*c4+2]=w[2]; v[4*c4+3]=w[3]; }
      u32 hi[8]; cvt16(v, hi);
      u32* dh = (u32*)(sA + am*LDP + akh);
#pragma unroll
      for (int q = 0; q < 8; ++q) dh[q] = hi[q];
    }
    {
      const float* bp = x + (size_t)(k0 + bkh)*65536 + (tn*128 + bn);
      float v[16];
#pragma unroll
      for (int i = 0; i < 16; ++i) v[i] = bp[(size_t)i*65536];
      u32 hi[8]; cvt16(v, hi);
      u32* dh = (u32*)(sB + bn*LDP + bkh);
#pragma unroll
      for (int q = 0; q < 8; ++q) dh[q] = hi[q];
    }
    __syncthreads();
    short8 af[4], bfr[4];
#pragma unroll
    for (int mi = 0; mi < 4; ++mi)
      af[mi] = *(const short8*)(sA + (wr*64 + mi*16 + lr)*LDP + lq*8);
#pragma unroll
    for (int ni = 0; ni < 4; ++ni)
      bfr[ni] = *(const short8*)(sB + (wc*64 + ni*16 + lr)*LDP + lq*8);
#pragma unroll
    for (int mi = 0; mi < 4; ++mi)
#pragma unroll
      for (int ni = 0; ni < 4; ++ni)
        acc[mi][ni] = __builtin_amdgcn_mfma_f32_16x16x32_bf16(af[mi], bfr[ni], acc[mi][ni], 0,0,0);
    __syncthreads();
  }
  const int rbase = tm*128 + wr*64, cbase = tn*128 + wc*64;
#pragma unroll
  for (int mi = 0; mi < 4; ++mi)
#pragma unroll
    for (int ni = 0; ni < 4; ++ni) {
      const int r0 = rbase + mi*16 + lq*4, cc = cbase + ni*16 + lr;
#pragma unroll
      for (int r = 0; r < 4; ++r)
        hout[(size_t)(r0 + r)*65536 + cc] = f2bf(acc[mi][ni][r]);
    }
}

// ---------------------------------------------------------------------------
// attn: out[c,i,j] = x[c,i,j] + sum_k h[c,i,k] * (P[c,k,j] * R_blk(k),j)
// P bf16 strided staging with per-column rescale from stats.
// ---------------------------------------------------------------------------
__global__ __launch_bounds__(256)
void attn_kernel(const u16* __restrict__ Hg, const u16* __restrict__ Pg,
                 const char* __restrict__ statsb, const float* __restrict__ Xg,
                 float* __restrict__ Og)
{
  __shared__ u16 sA[128*LDP], sB[128*LDP];
  const int c = blockIdx.y;
  const size_t cb = (size_t)c * 65536;
  const int tm = blockIdx.x >> 1, tn = blockIdx.x & 1;
  const int t = threadIdx.x, lane = t & 63, wid = t >> 6;
  const int wr = wid >> 1, wc = wid & 1, lr = lane & 15, lq = lane >> 4;
  const int am = t >> 1, akh = (t & 1) << 4;
  const int bn = t & 127, bkh = (t >> 7) << 4;

  // per-thread column rescale factors (column j = tn*128 + bn)
  const int j = tn*128 + bn;
  float2 s0 = *(const float2*)(statsb + (size_t)c*131072 + (size_t)j*8);
  float2 s1 = *(const float2*)(statsb + (size_t)c*131072 + 65536 + (size_t)j*8);
  float M = fmaxf(s0.x, s1.x);
  float e0 = __expf(s0.x - M), e1 = __expf(s1.x - M);
  float rd = 1.f / (s0.y * e0 + s1.y * e1);
  float R0 = e0 * rd, R1 = e1 * rd;

  f32x4 acc[4][4];
#pragma unroll
  for (int i = 0; i < 4; ++i)
#pragma unroll
    for (int k = 0; k < 4; ++k) acc[i][k] = (f32x4){0,0,0,0};

  for (int k0 = 0; k0 < 256; k0 += 32) {
    { // A: h bf16 copy
      const u16* hp = Hg + cb + (size_t)(tm*128 + am)*256 + k0 + akh;
      *(short8*)(sA + am*LDP + akh)     = *(const short8*)hp;
      *(short8*)(sA + am*LDP + akh + 8) = *(const short8*)(hp + 8);
    }
    { // B: P bf16 strided, rescale, re-round
      const float R = (k0 < 128) ? R0 : R1;
      const u16* pp = Pg + cb + (size_t)(k0 + bkh)*256 + j;
      float v[16];
#pragma unroll
      for (int i = 0; i < 16; ++i)
        v[i] = __uint_as_float(((u32)pp[(size_t)i*256]) << 16) * R;
      u32 hi[8]; cvt16(v, hi);
      u32* dh = (u32*)(sB + bn*LDP + bkh);
#pragma unroll
      for (int q = 0; q < 8; ++q) dh[q] = hi[q];
    }
    __syncthreads();
    short8 af[4], bfr[4];
#pragma unroll
    for (int mi = 0; mi < 4; ++mi)
      af[mi] = *(const short8*)(sA + (wr*64 + mi*16 + lr)*LDP + lq*8);
#pragma unroll
    for (int ni = 0; ni < 4; ++ni)
      bfr[ni] = *(const short8*)(sB + (wc*64 + ni*16 + lr)*LDP + lq*8);
#pragma unroll
    for (int mi = 0; mi < 4; ++mi)
#pragma unroll
      for (int ni = 0; ni < 4; ++ni)
        acc[mi][ni] = __builtin_amdgcn_mfma_f32_16x16x32_bf16(af[mi], bfr[ni], acc[mi][ni], 0,0,0);
    __syncthreads();
  }

  const float* Xc = Xg + cb; float* Oc = Og + cb;
  const int rbase = tm*128 + wr*64, cbase = tn*128 + wc*64;
#pragma unroll
  for (int mi = 0; mi < 4; ++mi)
#pragma unroll
    for (int ni = 0; ni < 4; ++ni) {
      const int r0 = rbase + mi*16 + lq*4, cc = cbase + ni*16 + lr;
#pragma unroll
      for (int r = 0; r < 4; ++r) {
        const size_t idx = (size_t)(r0 + r)*256 + cc;
        Oc[idx] = Xc[idx] + acc[mi][ni][r];
      }
    }
}

// ---------------------------------------------------------------------------
extern "C" void kernel_launch(void* const* d_in, const int* in_sizes, int n_in,
                              void* d_out, int out_size, void* d_ws, size_t ws_size,
                              hipStream_t stream)
{
  (void)in_sizes; (void)n_in; (void)out_size; (void)ws_size;
  const float* x  = (const float*)d_in[0];
  const float* Wf = (const float*)d_in[1];
  const float* Wg = (const float*)d_in[2];
  const float* Wh = (const float*)d_in[3];
  float* out = (float*)d_out;
  char*  ws  = (char*)d_ws;

  u16*   fhi  = (u16*)ws;                       // 67 MB; becomes P in place
  u16*   flo  = (u16*)(ws + 67108864);          // 67 MB; rows 0-3/128-131 reused as stats
  float* gbuf = (float*)(ws + 134217728);       // 134 MB fp32 g
  u16*   hbuf = (u16*)(ws + 134217728);         // h overwrites g after scores
  char*  statsb = ws + 67108864;                // stats live inside flo's own rows

  dim3 blk(256,1,1);
  conv_fg<<<dim3(4096,1,1), blk, 0, stream>>>(Wf, Wg, x, fhi, flo, gbuf);
  scores_kernel<<<dim3(1024,1,1), dim3(512,1,1), 0, stream>>>(fhi, flo, gbuf, statsb);
  conv_h<<<dim3(2048,1,1), blk, 0, stream>>>(Wh, x, hbuf);
  attn_kernel<<<dim3(4,512,1), blk, 0, stream>>>(hbuf, fhi, statsb, x, out);
}